// Round 5
// baseline (417.531 us; speedup 1.0000x reference)
//
#include <hip/hip_runtime.h>

// VCDN cross-feature matvec: out[c] = relu(W[c,:] @ cfdt + b[c])
// cfdt[(a*2304)+bb] = p01[a] * p23[bb]  (rank-1, never materialized)
// Memory floor: W = 339.7 MB fp32 read once ~ 54 us @ 6.3 TB/s.
// Round 5: MLP fix — launch_bounds(256,4) (128-VGPR cap), q back to LDS,
// explicit double-buffered row prefetch (18 outstanding dwordx4/wave).
// Grid 1024 = 4 blocks/CU x 4 waves = 16 waves/CU, all-resident, zero tail.

#define N_CLASSES 16
#define VIEW_DIM  48
#define P         2304            // 48*48 (row length in floats)
#define ROW_F4    (P / 4)         // 576 float4 per row
#define ROWS_PER_BLOCK 36
#define CHUNKS    (P / ROWS_PER_BLOCK)   // 64 blocks per class -> grid 1024
#define ROWS_PER_WAVE  9          // 4 waves per block
#define BLOCK     256
#define ITERS     (ROW_F4 / 64)   // 9 float4 per lane per row

typedef float v4f __attribute__((ext_vector_type(4)));

__global__ __launch_bounds__(BLOCK, 4) void vcdn_main(
        const float* __restrict__ x,
        const float* __restrict__ W,
        float* __restrict__ ws) {
    __shared__ float p23[P];

    const float* x0 = x;
    const float* x1 = x + VIEW_DIM;
    const float* x2 = x + 2 * VIEW_DIM;
    const float* x3 = x + 3 * VIEW_DIM;

    for (int t = threadIdx.x; t < P; t += BLOCK) {
        int i = t / VIEW_DIM;
        int j = t - i * VIEW_DIM;
        p23[t] = x2[i] * x3[j];
    }
    __syncthreads();

    const int c     = blockIdx.x / CHUNKS;
    const int chunk = blockIdx.x - c * CHUNKS;
    const int wid   = threadIdx.x >> 6;
    const int lane  = threadIdx.x & 63;

    const v4f* q4 = (const v4f*)p23;          // q stays in LDS (frees 36 VGPRs)
    const v4f* Wbase = (const v4f*)(W + (size_t)c * (size_t)P * P);

    const int row0 = chunk * ROWS_PER_BLOCK + wid * ROWS_PER_WAVE;

    // Double-buffered row prefetch: 2 x 9 x v4f = 72 VGPRs of load buffers.
    v4f wb[2][ITERS];
    {
        const v4f* Wr = Wbase + (size_t)row0 * ROW_F4;
#pragma unroll
        for (int it = 0; it < ITERS; ++it)
            wb[0][it] = __builtin_nontemporal_load(Wr + it * 64 + lane);
    }

    float acc = 0.0f;
#pragma unroll
    for (int r = 0; r < ROWS_PER_WAVE; ++r) {
        const int cur = r & 1;
        if (r + 1 < ROWS_PER_WAVE) {          // prefetch next row while computing
            const v4f* Wn = Wbase + (size_t)(row0 + r + 1) * ROW_F4;
#pragma unroll
            for (int it = 0; it < ITERS; ++it)
                wb[cur ^ 1][it] = __builtin_nontemporal_load(Wn + it * 64 + lane);
        }

        const int a = row0 + r;
        const int i = a / VIEW_DIM;
        const int j = a - i * VIEW_DIM;
        const float s01 = x0[i] * x1[j];      // wave-uniform scalar

        float racc = 0.0f;
#pragma unroll
        for (int it = 0; it < ITERS; ++it) {
            v4f q = q4[it * 64 + lane];       // ds_read_b128, 2-way alias = free
            v4f w = wb[cur][it];
            racc += w.x * q.x + w.y * q.y + w.z * q.z + w.w * q.w;
        }
        acc += s01 * racc;
    }

    // wave64 reduce, then 4 waves -> 1 value, pure store
    for (int off = 32; off; off >>= 1)
        acc += __shfl_down(acc, off, 64);

    __shared__ float wsum[BLOCK / 64];
    if (lane == 0) wsum[wid] = acc;
    __syncthreads();
    if (threadIdx.x == 0)
        ws[c * CHUNKS + chunk] = wsum[0] + wsum[1] + wsum[2] + wsum[3];
}

__global__ void vcdn_finalize(const float* __restrict__ ws,
                              const float* __restrict__ b,
                              float* __restrict__ out) {
    __shared__ float s[BLOCK];
    const int t   = threadIdx.x;
    const int c   = t >> 4;        // 16 threads per class
    const int sub = t & 15;
    float sum = 0.0f;
    for (int k = sub; k < CHUNKS; k += 16)     // 64/16 = 4 partials each
        sum += ws[c * CHUNKS + k];
    s[t] = sum;
    __syncthreads();
    if (t < N_CLASSES) {
        float tot = 0.0f;
#pragma unroll
        for (int k = 0; k < 16; ++k) tot += s[t * 16 + k];
        tot += b[t];
        out[t] = tot > 0.0f ? tot : 0.0f;
    }
}

extern "C" void kernel_launch(void* const* d_in, const int* in_sizes, int n_in,
                              void* d_out, int out_size, void* d_ws, size_t ws_size,
                              hipStream_t stream) {
    const float* x = (const float*)d_in[0];   // (4, 48) fp32
    const float* W = (const float*)d_in[1];   // (16, D) fp32
    const float* b = (const float*)d_in[2];   // (16,) fp32
    float* out = (float*)d_out;               // (16,) fp32
    float* ws  = (float*)d_ws;                // partials: 16*64 floats

    vcdn_main<<<N_CLASSES * CHUNKS, BLOCK, 0, stream>>>(x, W, ws);
    vcdn_finalize<<<1, BLOCK, 0, stream>>>(ws, b, out);
}